// Round 12
// baseline (496.712 us; speedup 1.0000x reference)
//
#include <hip/hip_runtime.h>

#define N_NODES 100000
#define NPAD    100096       // row count padded to 128-multiple (slab stride)
#define N_EDGES 1600000
#define SSHIFT 10
#define SNODES 1024          // nodes per slice (power of 2)
#define NSLICE 98            // ceil(N_NODES / SNODES)
#define CAP    18432         // per-slice pair capacity
#define ACHUNK 2048          // edges per bucket block
#define NACH   782           // ceil(N_EDGES / ACHUNK)
#define NWPREP 384
#define NCVT   6250          // 1.6M cvt threads / 256

typedef _Float16 f16;
typedef _Float16 f16x4 __attribute__((ext_vector_type(4)));
typedef _Float16 f16x8 __attribute__((ext_vector_type(8)));
typedef float f32x4 __attribute__((ext_vector_type(4)));

struct WPack { const float* w[6]; f16* o[6]; };

// Feature buffers are SLAB layout: slab g (features g*16..g*16+15) = [NPAD][16] f16,
// slab stride NPAD*16 f16 (3.2MB). Slab g is gathered only by blocks with blockIdx&7==g
// -> pins to one XCD's L2 (round-robin dispatch heuristic).

// ---------------- phase A: bucket by dst-slice + wprep + x->fp16 slab cvt ----------------
__global__ void bucket_cvt_kernel(const int* __restrict__ ei, int2* __restrict__ bpair,
                                  int* __restrict__ scur, WPack p,
                                  const float* __restrict__ x, f16* __restrict__ x16) {
  __shared__ int lcnt[NSLICE];
  __shared__ int lbase[NSLICE];
  int b = blockIdx.x;
  if (b < NACH) {
    if (threadIdx.x < NSLICE) lcnt[threadIdx.x] = 0;
    __syncthreads();
    int base = b * ACHUNK;
    int msrc[8], mdst[8], mrank[8], msl[8];
    #pragma unroll
    for (int j = 0; j < 8; ++j) {
      int i = base + j * 256 + threadIdx.x;
      msl[j] = -1;
      if (i < N_EDGES) {
        msrc[j] = ei[i];
        int d = ei[N_EDGES + i];
        mdst[j] = d;
        int sl = d >> SSHIFT;
        msl[j] = sl;
        mrank[j] = atomicAdd(&lcnt[sl], 1);
      }
    }
    __syncthreads();
    if (threadIdx.x < NSLICE) lbase[threadIdx.x] = atomicAdd(&scur[threadIdx.x], lcnt[threadIdx.x]);
    __syncthreads();
    #pragma unroll
    for (int j = 0; j < 8; ++j) {
      if (msl[j] >= 0)
        bpair[(size_t)msl[j] * CAP + lbase[msl[j]] + mrank[j]] = make_int2(msrc[j], mdst[j]);
    }
  } else if (b < NACH + NWPREP) {
    // weight prep: Wt[c*128 + k] = (f16)W[k*128 + c]  (plain transpose)
    int bb = b - NACH;
    int wi = bb >> 6;
    int t = (bb & 63) * 256 + threadIdx.x;  // 0..16383
    int k = t >> 7;
    int c = t & 127;
    p.o[wi][c * 128 + k] = (f16)p.w[wi][t];
  } else {
    // cvt into slab layout: idx = g*200000 + r*2 + half
    int idx = (b - NACH - NWPREP) * 256 + threadIdx.x;  // 0..1599999
    int g = idx / 200000;
    int rh = idx - g * 200000;
    int r = rh >> 1, half = rh & 1;
    const float* xs = x + r * 128 + g * 16 + half * 8;
    float4 a0 = *(const float4*)(xs);
    float4 a1 = *(const float4*)(xs + 4);
    f16x8 v = {(f16)a0.x, (f16)a0.y, (f16)a0.z, (f16)a0.w,
               (f16)a1.x, (f16)a1.y, (f16)a1.z, (f16)a1.w};
    *(f16x8*)(x16 + (size_t)g * (NPAD * 16) + r * 16 + half * 8) = v;
  }
}

// ---------------- phase B: per-slice CSR via LDS hist + scan + cursors ----------------
__global__ __launch_bounds__(1024)
void csr_slice_kernel(const int2* __restrict__ bpair, const int* __restrict__ scur,
                      int* __restrict__ offs, int* __restrict__ counts,
                      int* __restrict__ srcs) {
  __shared__ int hist[SNODES];
  __shared__ int sb[128];
  __shared__ int sd[1024];
  const int s = blockIdx.x;
  const int t = threadIdx.x;
  if (t < SNODES) hist[t] = 0;
  if (t < NSLICE) sb[t] = scur[t];
  __syncthreads();
  const int cnt = sb[s];
  int base = 0;
  for (int q = 0; q < NSLICE; ++q) base += (q < s) ? sb[q] : 0;

  const int2* p = bpair + (size_t)s * CAP;
  for (int i = t; i < cnt; i += 1024) atomicAdd(&hist[p[i].y & (SNODES - 1)], 1);
  __syncthreads();

  int loc = (t < SNODES) ? hist[t] : 0;
  sd[t] = loc;
  __syncthreads();
  for (int o = 1; o < 1024; o <<= 1) {
    int xv = (t >= o) ? sd[t - o] : 0;
    __syncthreads();
    sd[t] += xv;
    __syncthreads();
  }
  int run = sd[t] - loc;
  if (t < SNODES) {
    int node = s * SNODES + t;
    if (node < N_NODES) { offs[node] = base + run; counts[node] = loc; }
    hist[t] = run;
  }
  __syncthreads();

  for (int i = t; i < cnt; i += 1024) {
    int2 pr = p[i];
    int pos = base + atomicAdd(&hist[pr.y & (SNODES - 1)], 1);
    srcs[pos] = pr.x;
  }
}

// ---------------- aggregation (slab, XCD-pinned): z[g][i] = h[g][i] + sum h[g][src] ----------------
// blockIdx&7 = slab g; 2-lane team per node; gathers are 32B within the 3.2MB slab (L2-hit).
__global__ void aggregate_kernel(const f16* __restrict__ h, const int* __restrict__ offs,
                                 const int* __restrict__ deg, const int* __restrict__ srcs,
                                 f16* __restrict__ z, int n) {
  int team = threadIdx.x >> 1;
  int ll = threadIdx.x & 1;
  int g = blockIdx.x & 7;
  int node = (int)(blockIdx.x >> 3) * 128 + team;
  if (node >= n) return;
  const f16* hs = h + (size_t)g * (NPAD * 16);
  f16* zs = z + (size_t)g * (NPAD * 16);
  int beg = offs[node];
  int d = deg[node];
  f16x8 hv = *(const f16x8*)(hs + node * 16 + ll * 8);
  float acc[8];
  #pragma unroll
  for (int q = 0; q < 8; ++q) acc[q] = (float)hv[q];
  int j = 0;
  for (; j + 4 <= d; j += 4) {
    int s0 = srcs[beg + j + 0];
    int s1 = srcs[beg + j + 1];
    int s2 = srcs[beg + j + 2];
    int s3 = srcs[beg + j + 3];
    f16x8 a0 = *(const f16x8*)(hs + s0 * 16 + ll * 8);
    f16x8 a1 = *(const f16x8*)(hs + s1 * 16 + ll * 8);
    f16x8 a2 = *(const f16x8*)(hs + s2 * 16 + ll * 8);
    f16x8 a3 = *(const f16x8*)(hs + s3 * 16 + ll * 8);
    #pragma unroll
    for (int q = 0; q < 8; ++q)
      acc[q] += ((float)a0[q] + (float)a1[q]) + ((float)a2[q] + (float)a3[q]);
  }
  for (; j < d; ++j) {
    int s = srcs[beg + j];
    f16x8 a = *(const f16x8*)(hs + s * 16 + ll * 8);
    #pragma unroll
    for (int q = 0; q < 8; ++q) acc[q] += (float)a[q];
  }
  f16x8 o;
  #pragma unroll
  for (int q = 0; q < 8; ++q) o[q] = (f16)acc[q];
  *(f16x8*)(zs + node * 16 + ll * 8) = o;
}

// ---------------- fused GIN layer: fragments direct from global (L1/L2); LDS only for h1 ----------------
// 512 threads = 8 waves (2 row-groups x 4 col-groups). Swapped-MFMA (transposed fragments).
template <int FUSE>
__global__ __launch_bounds__(512, 4)
void layer_kernel(const f16* __restrict__ A, const f16* __restrict__ W1t,
                  const f16* __restrict__ W2t,
                  const float* __restrict__ bias1, const float* __restrict__ bias2,
                  void* __restrict__ outv,
                  const float* __restrict__ wout, const float* __restrict__ bout, int n) {
  __shared__ f16 Az[128 * 128];  // 32KB: h1 exchange (chunk-XOR swizzled), then h2 staging
  const int t = threadIdx.x;
  const int lane = t & 63;
  const int w = t >> 6;
  const int rowBase = blockIdx.x * 128;
  const int wr = w >> 2;         // 0..1 row group (64 rows)
  const int wc = w & 3;          // 0..3 col group (32 cols)
  const int ls = lane & 15, lg = lane >> 4;

  f32x4 acc[2][4];
  #pragma unroll
  for (int m = 0; m < 2; ++m)
    #pragma unroll
    for (int nn = 0; nn < 4; ++nn)
      acc[m][nn] = (f32x4){0.f, 0.f, 0.f, 0.f};

  // ---- phase 1: h1^T = (A @ W1)^T, operands straight from global ----
  #pragma unroll
  for (int ks = 0; ks < 4; ++ks) {
    f16x8 wf[2], af[4];
    #pragma unroll
    for (int m = 0; m < 2; ++m) {
      int c = wc * 32 + m * 16 + ls;
      wf[m] = *(const f16x8*)(W1t + c * 128 + ks * 32 + lg * 8);
    }
    #pragma unroll
    for (int nn = 0; nn < 4; ++nn) {
      int r = rowBase + wr * 64 + nn * 16 + ls;
      int slab = ks * 2 + (lg >> 1);
      af[nn] = *(const f16x8*)(A + (size_t)slab * (NPAD * 16) + (size_t)r * 16 + (lg & 1) * 8);
    }
    #pragma unroll
    for (int m = 0; m < 2; ++m)
      #pragma unroll
      for (int nn = 0; nn < 4; ++nn)
        acc[m][nn] = __builtin_amdgcn_mfma_f32_16x16x32_f16(wf[m], af[nn], acc[m][nn], 0, 0, 0);
  }

  // ---- h1 (relu+bias1) -> Az (swizzled, packed b64) ----
  #pragma unroll
  for (int m = 0; m < 2; ++m) {
    int c = wc * 32 + m * 16 + lg * 4;
    float b0 = bias1[c + 0], b1v = bias1[c + 1], b2v_ = bias1[c + 2], b3 = bias1[c + 3];
    #pragma unroll
    for (int nn = 0; nn < 4; ++nn) {
      int r = wr * 64 + nn * 16 + ls;
      f16x4 pv = {(f16)fmaxf(acc[m][nn][0] + b0, 0.f),
                  (f16)fmaxf(acc[m][nn][1] + b1v, 0.f),
                  (f16)fmaxf(acc[m][nn][2] + b2v_, 0.f),
                  (f16)fmaxf(acc[m][nn][3] + b3, 0.f)};
      *(f16x4*)((char*)Az + r * 256 + ((((c >> 3)) ^ (r & 7)) << 4) + (c & 7) * 2) = pv;
    }
  }
  __syncthreads();

  // ---- phase 2: h2^T = (h1 @ W2)^T; h1 from LDS, W2 from global ----
  #pragma unroll
  for (int m = 0; m < 2; ++m)
    #pragma unroll
    for (int nn = 0; nn < 4; ++nn)
      acc[m][nn] = (f32x4){0.f, 0.f, 0.f, 0.f};
  #pragma unroll
  for (int ks = 0; ks < 4; ++ks) {
    f16x8 wf[2], hf[4];
    #pragma unroll
    for (int m = 0; m < 2; ++m) {
      int c = wc * 32 + m * 16 + ls;
      wf[m] = *(const f16x8*)(W2t + c * 128 + ks * 32 + lg * 8);
    }
    #pragma unroll
    for (int nn = 0; nn < 4; ++nn) {
      int r = wr * 64 + nn * 16 + ls;
      int ch = (ks * 4 + lg) ^ (r & 7);
      hf[nn] = *(const f16x8*)((const char*)Az + r * 256 + (ch << 4));
    }
    #pragma unroll
    for (int m = 0; m < 2; ++m)
      #pragma unroll
      for (int nn = 0; nn < 4; ++nn)
        acc[m][nn] = __builtin_amdgcn_mfma_f32_16x16x32_f16(wf[m], hf[nn], acc[m][nn], 0, 0, 0);
  }

  if (FUSE) {
    float s_[4] = {0.f, 0.f, 0.f, 0.f};
    #pragma unroll
    for (int m = 0; m < 2; ++m) {
      int c = wc * 32 + m * 16 + lg * 4;
      float bb[4], wv[4];
      #pragma unroll
      for (int i = 0; i < 4; ++i) { bb[i] = bias2[c + i]; wv[i] = wout[c + i]; }
      #pragma unroll
      for (int nn = 0; nn < 4; ++nn)
        #pragma unroll
        for (int i = 0; i < 4; ++i)
          s_[nn] += fmaxf(acc[m][nn][i] + bb[i], 0.f) * wv[i];
    }
    #pragma unroll
    for (int nn = 0; nn < 4; ++nn) {
      s_[nn] += __shfl_xor(s_[nn], 16);
      s_[nn] += __shfl_xor(s_[nn], 32);
    }
    __syncthreads();
    float* red = (float*)Az;  // [128][4]
    if (lg == 0) {
      #pragma unroll
      for (int nn = 0; nn < 4; ++nn) red[(wr * 64 + nn * 16 + ls) * 4 + wc] = s_[nn];
    }
    __syncthreads();
    if (t < 128) {
      int gr = rowBase + t;
      if (gr < n)
        ((float*)outv)[gr] = red[t * 4] + red[t * 4 + 1] + red[t * 4 + 2] + red[t * 4 + 3] + bout[0];
    }
  } else {
    __syncthreads();  // phase-2 Az reads complete before overwrite
    #pragma unroll
    for (int m = 0; m < 2; ++m) {
      int c = wc * 32 + m * 16 + lg * 4;
      float b0 = bias2[c + 0], b1v = bias2[c + 1], b2v_ = bias2[c + 2], b3 = bias2[c + 3];
      #pragma unroll
      for (int nn = 0; nn < 4; ++nn) {
        int r = wr * 64 + nn * 16 + ls;
        f16x4 pv = {(f16)fmaxf(acc[m][nn][0] + b0, 0.f),
                    (f16)fmaxf(acc[m][nn][1] + b1v, 0.f),
                    (f16)fmaxf(acc[m][nn][2] + b2v_, 0.f),
                    (f16)fmaxf(acc[m][nn][3] + b3, 0.f)};
        *(f16x4*)((char*)Az + r * 256 + ((((c >> 3)) ^ (r & 7)) << 4) + (c & 7) * 2) = pv;
      }
    }
    __syncthreads();
    // copy-out to slab layout: logical chunk (g*2+half) of row r at LDS pos ^(r&7)
    f16* out = (f16*)outv;
    #pragma unroll
    for (int it = 0; it < 4; ++it) {
      int idx = it * 512 + t;   // 0..2047
      int g = idx >> 8;
      int rh = idx & 255;
      int r = rh >> 1, half = rh & 1;
      int ch = (g * 2 + half) ^ (r & 7);
      f16x8 v = *(const f16x8*)((const char*)Az + r * 256 + (ch << 4));
      *(f16x8*)(out + (size_t)g * (NPAD * 16) + (size_t)(rowBase + r) * 16 + half * 8) = v;
    }
  }
}

// ---------------- launch ----------------

extern "C" void kernel_launch(void* const* d_in, const int* in_sizes, int n_in,
                              void* d_out, int out_size, void* d_ws, size_t ws_size,
                              hipStream_t stream) {
  const float* x = (const float*)d_in[0];
  const int* ei = (const int*)d_in[1];
  const float* w1[3] = {(const float*)d_in[2], (const float*)d_in[6], (const float*)d_in[10]};
  const float* b1[3] = {(const float*)d_in[3], (const float*)d_in[7], (const float*)d_in[11]};
  const float* w2[3] = {(const float*)d_in[4], (const float*)d_in[8], (const float*)d_in[12]};
  const float* b2[3] = {(const float*)d_in[5], (const float*)d_in[9], (const float*)d_in[13]};
  const float* wout = (const float*)d_in[14];
  const float* bout = (const float*)d_in[15];
  float* out = (float*)d_out;

  char* ws = (char*)d_ws;
  size_t off = 0;
  f16* B0  = (f16*)(ws + off); off += (size_t)NPAD * 128 * 2;
  f16* B1  = (f16*)(ws + off); off += (size_t)NPAD * 128 * 2;
  f16* x16 = (f16*)(ws + off); off += (size_t)NPAD * 128 * 2;
  f16* Wt[6];
  for (int i = 0; i < 6; ++i) { Wt[i] = (f16*)(ws + off); off += 128 * 128 * 2; }
  int* offs   = (int*)(ws + off); off += (size_t)N_NODES * 4;
  int* counts = (int*)(ws + off); off += (size_t)N_NODES * 4;
  int* scur   = (int*)(ws + off); off += 1024;
  int* srcs   = (int*)(ws + off); off += (size_t)N_EDGES * 4;
  int2* bpair = (int2*)(ws + off); off += (size_t)NSLICE * CAP * 8;

  hipMemsetAsync(scur, 0, 1024, stream);
  WPack wp;
  const float* wsrc[6] = {w1[0], w2[0], w1[1], w2[1], w1[2], w2[2]};
  for (int i = 0; i < 6; ++i) { wp.w[i] = wsrc[i]; wp.o[i] = Wt[i]; }
  bucket_cvt_kernel<<<NACH + NWPREP + NCVT, 256, 0, stream>>>(ei, bpair, scur, wp, x, x16);
  csr_slice_kernel<<<NSLICE, 1024, 0, stream>>>(bpair, scur, offs, counts, srcs);

  int aggGrid = 8 * ((N_NODES + 127) / 128);  // 6256: slab g = blockIdx&7 (XCD-pinned)
  int lyrGrid = (N_NODES + 127) / 128;        // 782

  // layer 1
  aggregate_kernel<<<aggGrid, 256, 0, stream>>>(x16, offs, counts, srcs, B0, N_NODES);
  layer_kernel<0><<<lyrGrid, 512, 0, stream>>>(B0, Wt[0], Wt[1], b1[0], b2[0], B1, nullptr, nullptr, N_NODES);
  // layer 2
  aggregate_kernel<<<aggGrid, 256, 0, stream>>>(B1, offs, counts, srcs, B0, N_NODES);
  layer_kernel<0><<<lyrGrid, 512, 0, stream>>>(B0, Wt[2], Wt[3], b1[1], b2[1], B1, nullptr, nullptr, N_NODES);
  // layer 3 (+ fused w_out projection)
  aggregate_kernel<<<aggGrid, 256, 0, stream>>>(B1, offs, counts, srcs, B0, N_NODES);
  layer_kernel<1><<<lyrGrid, 512, 0, stream>>>(B0, Wt[4], Wt[5], b1[2], b2[2], out, wout, bout, N_NODES);
}

// Round 13
// 394.531 us; speedup vs baseline: 1.2590x; 1.2590x over previous
//
#include <hip/hip_runtime.h>

#define N_NODES 100000
#define N_EDGES 1600000
#define SSHIFT 10
#define SNODES 1024          // nodes per slice (power of 2)
#define NSLICE 98            // ceil(N_NODES / SNODES)
#define CAP    18432         // per-slice pair capacity (expected 16327 + ~16 sigma)
#define ACHUNK 2048          // edges per bucket block
#define NACH   782           // ceil(N_EDGES / ACHUNK)
#define NWPREP 384           // wprep blocks
#define NCVT   6250          // cvt blocks (N_NODES*16 chunks / 256)

typedef _Float16 f16;
typedef _Float16 f16x2 __attribute__((ext_vector_type(2)));
typedef _Float16 f16x4 __attribute__((ext_vector_type(4)));
typedef _Float16 f16x8 __attribute__((ext_vector_type(8)));
typedef float f32x4 __attribute__((ext_vector_type(4)));

struct WPack { const float* w[6]; f16* o[6]; };

// All feature buffers (x16, B0, B1) are stored CHUNK-SWIZZLED per row:
// logical 16B-chunk c of row r lives at byte offset (c ^ (r & 7)) * 16 within the row.
// This lets layer_kernel stage A with linear global_load_lds.

// ---------------- phase A: bucket by dst-slice + wprep + x->fp16 swizzled cvt ----------------
__global__ void bucket_cvt_kernel(const int* __restrict__ ei, int2* __restrict__ bpair,
                                  int* __restrict__ scur, WPack p,
                                  const float* __restrict__ x, f16* __restrict__ x16) {
  __shared__ int lcnt[NSLICE];
  __shared__ int lbase[NSLICE];
  int b = blockIdx.x;
  if (b < NACH) {
    if (threadIdx.x < NSLICE) lcnt[threadIdx.x] = 0;
    __syncthreads();
    int base = b * ACHUNK;
    int msrc[8], mdst[8], mrank[8], msl[8];
    #pragma unroll
    for (int j = 0; j < 8; ++j) {
      int i = base + j * 256 + threadIdx.x;
      msl[j] = -1;
      if (i < N_EDGES) {
        msrc[j] = ei[i];
        int d = ei[N_EDGES + i];
        mdst[j] = d;
        int sl = d >> SSHIFT;  // 0..97
        msl[j] = sl;
        mrank[j] = atomicAdd(&lcnt[sl], 1);  // LDS atomic
      }
    }
    __syncthreads();
    if (threadIdx.x < NSLICE) lbase[threadIdx.x] = atomicAdd(&scur[threadIdx.x], lcnt[threadIdx.x]);
    __syncthreads();
    #pragma unroll
    for (int j = 0; j < 8; ++j) {
      if (msl[j] >= 0)
        bpair[(size_t)msl[j] * CAP + lbase[msl[j]] + mrank[j]] = make_int2(msrc[j], mdst[j]);
    }
  } else if (b < NACH + NWPREP) {
    int bb = b - NACH;
    int wi = bb >> 6;
    int t = (bb & 63) * 256 + threadIdx.x;  // 0..16383
    int c = t >> 7;
    int i = t & 127;
    int kc = i >> 3, j = i & 7;
    int k = ((kc ^ (c & 7)) << 3) + j;
    p.o[wi][t] = (f16)p.w[wi][k * 128 + c];
  } else {
    // cvt: one 16B chunk per thread, swizzled write
    int tt = (b - NACH - NWPREP) * 256 + threadIdx.x;  // 0..1599999
    int r = tt >> 4, c = tt & 15;
    const float* xs = x + r * 128 + c * 8;
    float4 a0 = *(const float4*)(xs);
    float4 a1 = *(const float4*)(xs + 4);
    f16x8 v = {(f16)a0.x, (f16)a0.y, (f16)a0.z, (f16)a0.w,
               (f16)a1.x, (f16)a1.y, (f16)a1.z, (f16)a1.w};
    *(f16x8*)(x16 + r * 128 + ((c ^ (r & 7)) << 3)) = v;
  }
}

// ---------------- phase B: per-slice CSR via LDS hist + scan + cursors (1024 thr) ----------------
__global__ __launch_bounds__(1024)
void csr_slice_kernel(const int2* __restrict__ bpair, const int* __restrict__ scur,
                      int* __restrict__ offs, int* __restrict__ counts,
                      int* __restrict__ srcs) {
  __shared__ int hist[SNODES];   // 4KB: histogram -> exclusive prefix -> cursors
  __shared__ int sb[128];
  __shared__ int sd[1024];
  const int s = blockIdx.x;
  const int t = threadIdx.x;
  if (t < SNODES) hist[t] = 0;
  if (t < NSLICE) sb[t] = scur[t];
  __syncthreads();
  const int cnt = sb[s];
  int base = 0;
  for (int q = 0; q < NSLICE; ++q) base += (q < s) ? sb[q] : 0;  // broadcast LDS reads

  const int2* p = bpair + (size_t)s * CAP;
  // pass 1: histogram
  for (int i = t; i < cnt; i += 1024) atomicAdd(&hist[p[i].y & (SNODES - 1)], 1);
  __syncthreads();

  // block exclusive scan over 1024 hist entries (1 per thread)
  int loc = (t < SNODES) ? hist[t] : 0;
  sd[t] = loc;
  __syncthreads();
  for (int o = 1; o < 1024; o <<= 1) {
    int xv = (t >= o) ? sd[t - o] : 0;
    __syncthreads();
    sd[t] += xv;
    __syncthreads();
  }
  int run = sd[t] - loc;  // exclusive prefix
  if (t < SNODES) {
    int node = s * SNODES + t;
    if (node < N_NODES) { offs[node] = base + run; counts[node] = loc; }
    hist[t] = run;  // becomes cursor
  }
  __syncthreads();

  // pass 2: scatter srcs (LDS cursor atomics; contiguous single-owner output region)
  for (int i = t; i < cnt; i += 1024) {
    int2 pr = p[i];
    int pos = base + atomicAdd(&hist[pr.y & (SNODES - 1)], 1);
    srcs[pos] = pr.x;
  }
}

// ---------------- aggregation: z[i] = h[i] + sum_{j in N_in(i)} h[j]  (swizzled rows) ----------------
// 16-lane group per node; lane gl holds logical chunk gl (reads position gl^(row&7)).
// 4-wide unrolled gather: 4 independent 16B loads in flight per iteration.
__global__ void aggregate_kernel(const f16* __restrict__ h, const int* __restrict__ offs,
                                 const int* __restrict__ deg, const int* __restrict__ srcs,
                                 f16* __restrict__ z, int n) {
  int gid = (int)((blockIdx.x * blockDim.x + threadIdx.x) >> 4);
  int gl = threadIdx.x & 15;
  int lb = threadIdx.x & 48;  // group base lane within wave
  if (gid >= n) return;
  int beg = offs[gid];
  int d = deg[gid];
  f16x8 hv = *(const f16x8*)(h + (size_t)gid * 128 + ((gl ^ (gid & 7)) << 3));
  float acc[8];
  #pragma unroll
  for (int q = 0; q < 8; ++q) acc[q] = (float)hv[q];
  for (int base = 0; base < d; base += 16) {
    int cnt = min(16, d - base);
    int sv = (base + gl < d) ? srcs[beg + base + gl] : 0;  // one coalesced load / 16 edges
    int j = 0;
    for (; j + 4 <= cnt; j += 4) {
      int s0 = __shfl(sv, lb + j + 0);
      int s1 = __shfl(sv, lb + j + 1);
      int s2 = __shfl(sv, lb + j + 2);
      int s3 = __shfl(sv, lb + j + 3);
      f16x8 a0 = *(const f16x8*)(h + (size_t)s0 * 128 + ((gl ^ (s0 & 7)) << 3));
      f16x8 a1 = *(const f16x8*)(h + (size_t)s1 * 128 + ((gl ^ (s1 & 7)) << 3));
      f16x8 a2 = *(const f16x8*)(h + (size_t)s2 * 128 + ((gl ^ (s2 & 7)) << 3));
      f16x8 a3 = *(const f16x8*)(h + (size_t)s3 * 128 + ((gl ^ (s3 & 7)) << 3));
      #pragma unroll
      for (int q = 0; q < 8; ++q)
        acc[q] += ((float)a0[q] + (float)a1[q]) + ((float)a2[q] + (float)a3[q]);
    }
    for (; j < cnt; ++j) {
      int s = __shfl(sv, lb + j);
      f16x8 a = *(const f16x8*)(h + (size_t)s * 128 + ((gl ^ (s & 7)) << 3));
      #pragma unroll
      for (int q = 0; q < 8; ++q) acc[q] += (float)a[q];
    }
  }
  f16x8 o;
  #pragma unroll
  for (int q = 0; q < 8; ++q) o[q] = (f16)acc[q];
  *(f16x8*)(z + (size_t)gid * 128 + ((gl ^ (gid & 7)) << 3)) = o;
}

// ---------------- fused GIN layer, 512 threads (8 waves = 2 row-groups x 4 col-groups) ----------------
// h2 = relu(relu(A@W1+b1)@W2+b2), swapped-MFMA (computes transposed fragments).
// A and W1 staged via global_load_lds (both stored (pre-)swizzled in global -> linear LDS dest).
// W2 global_load_lds'd into Ws after phase-1 barrier (hides under h1 writeback).
template <int FUSE>
__global__ __launch_bounds__(512, 4)
void layer_kernel(const f16* __restrict__ A, const f16* __restrict__ W1t,
                  const f16* __restrict__ W2t,
                  const float* __restrict__ bias1, const float* __restrict__ bias2,
                  void* __restrict__ outv,
                  const float* __restrict__ wout, const float* __restrict__ bout, int n) {
  __shared__ f16 Az[128 * 128];  // 32KB: A -> h1 -> h2 (chunk-swizzled rows)
  __shared__ f16 Ws[128 * 128];  // 32KB: W1 -> W2 (pre-swizzled)
  const int t = threadIdx.x;
  const int lane = t & 63;
  const int w = t >> 6;          // 0..7
  const int rowBase = blockIdx.x * 128;
  const int wr = w >> 2;         // 0..1 : A-row group (64 rows)
  const int wc = w & 3;          // 0..3 : W-col group (32 cols)
  const int ls = lane & 15, lg = lane >> 4;

  // ---- stage A + W1 via global_load_lds (1KB per wave-instr, contiguous source) ----
  {
    const char* Ab = (const char*)A + (size_t)rowBase * 256;
    const char* Wb = (const char*)W1t;
    #pragma unroll
    for (int it = 0; it < 4; ++it) {
      int off = w * 4096 + it * 1024;
      __builtin_amdgcn_global_load_lds(
          (const __attribute__((address_space(1))) void*)(Ab + off + lane * 16),
          (__attribute__((address_space(3))) void*)((char*)Az + off), 16, 0, 0);
      __builtin_amdgcn_global_load_lds(
          (const __attribute__((address_space(1))) void*)(Wb + off + lane * 16),
          (__attribute__((address_space(3))) void*)((char*)Ws + off), 16, 0, 0);
    }
  }
  __syncthreads();  // drains vmcnt

  f32x4 acc[2][4];
  #pragma unroll
  for (int m = 0; m < 2; ++m)
    #pragma unroll
    for (int nn = 0; nn < 4; ++nn)
      acc[m][nn] = (f32x4){0.f, 0.f, 0.f, 0.f};

  // ---- phase 1: acc = h1^T fragments ----
  #pragma unroll
  for (int ks = 0; ks < 4; ++ks) {
    f16x8 wf[2], af[4];
    #pragma unroll
    for (int m = 0; m < 2; ++m) {
      int c = wc * 32 + m * 16 + ls;
      int ch = (ks * 4 + lg) ^ (c & 7);
      wf[m] = *(const f16x8*)((const char*)Ws + c * 256 + (ch << 4));
    }
    #pragma unroll
    for (int nn = 0; nn < 4; ++nn) {
      int r = wr * 64 + nn * 16 + ls;
      int ch = (ks * 4 + lg) ^ (r & 7);
      af[nn] = *(const f16x8*)((const char*)Az + r * 256 + (ch << 4));
    }
    #pragma unroll
    for (int m = 0; m < 2; ++m)
      #pragma unroll
      for (int nn = 0; nn < 4; ++nn)
        acc[m][nn] = __builtin_amdgcn_mfma_f32_16x16x32_f16(wf[m], af[nn], acc[m][nn], 0, 0, 0);
  }
  __syncthreads();  // all phase-1 LDS reads complete

  // ---- W2 -> Ws via global_load_lds (latency hides under h1 writeback) ----
  {
    const char* Wb = (const char*)W2t;
    #pragma unroll
    for (int it = 0; it < 4; ++it) {
      int off = w * 4096 + it * 1024;
      __builtin_amdgcn_global_load_lds(
          (const __attribute__((address_space(1))) void*)(Wb + off + lane * 16),
          (__attribute__((address_space(3))) void*)((char*)Ws + off), 16, 0, 0);
    }
  }
  // ---- h1 (relu+bias) -> Az swizzled, packed b64 ----
  #pragma unroll
  for (int m = 0; m < 2; ++m) {
    int c = wc * 32 + m * 16 + lg * 4;
    float b0 = bias1[c + 0], b1v = bias1[c + 1], b2v_ = bias1[c + 2], b3 = bias1[c + 3];
    #pragma unroll
    for (int nn = 0; nn < 4; ++nn) {
      int r = wr * 64 + nn * 16 + ls;
      f16x4 pv = {(f16)fmaxf(acc[m][nn][0] + b0, 0.f),
                  (f16)fmaxf(acc[m][nn][1] + b1v, 0.f),
                  (f16)fmaxf(acc[m][nn][2] + b2v_, 0.f),
                  (f16)fmaxf(acc[m][nn][3] + b3, 0.f)};
      *(f16x4*)((char*)Az + r * 256 + ((((c >> 3)) ^ (r & 7)) << 4) + (c & 7) * 2) = pv;
    }
  }
  __syncthreads();  // drains W2 vmcnt + h1 lgkm

  // ---- phase 2: acc = h2^T fragments ----
  #pragma unroll
  for (int m = 0; m < 2; ++m)
    #pragma unroll
    for (int nn = 0; nn < 4; ++nn)
      acc[m][nn] = (f32x4){0.f, 0.f, 0.f, 0.f};
  #pragma unroll
  for (int ks = 0; ks < 4; ++ks) {
    f16x8 wf[2], hf[4];
    #pragma unroll
    for (int m = 0; m < 2; ++m) {
      int c = wc * 32 + m * 16 + ls;
      int ch = (ks * 4 + lg) ^ (c & 7);
      wf[m] = *(const f16x8*)((const char*)Ws + c * 256 + (ch << 4));
    }
    #pragma unroll
    for (int nn = 0; nn < 4; ++nn) {
      int r = wr * 64 + nn * 16 + ls;
      int ch = (ks * 4 + lg) ^ (r & 7);
      hf[nn] = *(const f16x8*)((const char*)Az + r * 256 + (ch << 4));
    }
    #pragma unroll
    for (int m = 0; m < 2; ++m)
      #pragma unroll
      for (int nn = 0; nn < 4; ++nn)
        acc[m][nn] = __builtin_amdgcn_mfma_f32_16x16x32_f16(wf[m], hf[nn], acc[m][nn], 0, 0, 0);
  }

  if (FUSE) {
    // out[r] = sum_c relu(h2 + b2)[r][c] * wout[c] + bout
    float s_[4] = {0.f, 0.f, 0.f, 0.f};
    #pragma unroll
    for (int m = 0; m < 2; ++m) {
      int c = wc * 32 + m * 16 + lg * 4;
      float bb[4], wv[4];
      #pragma unroll
      for (int i = 0; i < 4; ++i) { bb[i] = bias2[c + i]; wv[i] = wout[c + i]; }
      #pragma unroll
      for (int nn = 0; nn < 4; ++nn)
        #pragma unroll
        for (int i = 0; i < 4; ++i)
          s_[nn] += fmaxf(acc[m][nn][i] + bb[i], 0.f) * wv[i];
    }
    #pragma unroll
    for (int nn = 0; nn < 4; ++nn) {
      s_[nn] += __shfl_xor(s_[nn], 16);
      s_[nn] += __shfl_xor(s_[nn], 32);
    }
    __syncthreads();  // Az/Ws reads complete
    float* red = (float*)Az;  // [128][4]
    if (lg == 0) {
      #pragma unroll
      for (int nn = 0; nn < 4; ++nn) red[(wr * 64 + nn * 16 + ls) * 4 + wc] = s_[nn];
    }
    __syncthreads();
    if (t < 128) {
      int gr = rowBase + t;
      if (gr < n)
        ((float*)outv)[gr] = red[t * 4] + red[t * 4 + 1] + red[t * 4 + 2] + red[t * 4 + 3] + bout[0];
    }
  } else {
    __syncthreads();  // phase-2 Az reads complete before overwrite
    #pragma unroll
    for (int m = 0; m < 2; ++m) {
      int c = wc * 32 + m * 16 + lg * 4;
      float b0 = bias2[c + 0], b1v = bias2[c + 1], b2v_ = bias2[c + 2], b3 = bias2[c + 3];
      #pragma unroll
      for (int nn = 0; nn < 4; ++nn) {
        int r = wr * 64 + nn * 16 + ls;
        f16x4 pv = {(f16)fmaxf(acc[m][nn][0] + b0, 0.f),
                    (f16)fmaxf(acc[m][nn][1] + b1v, 0.f),
                    (f16)fmaxf(acc[m][nn][2] + b2v_, 0.f),
                    (f16)fmaxf(acc[m][nn][3] + b3, 0.f)};
        *(f16x4*)((char*)Az + r * 256 + ((((c >> 3)) ^ (r & 7)) << 4) + (c & 7) * 2) = pv;
      }
    }
    __syncthreads();
    // linear copy-out: Az layout == swizzled global layout; lane-stride 16B (conflict-free)
    #pragma unroll
    for (int j = 0; j < 4; ++j) {
      int byteoff = t * 16 + j * 8192;
      int r = byteoff >> 8;
      if (rowBase + r < n) {
        f16x8 v = *(const f16x8*)((const char*)Az + byteoff);
        *(f16x8*)((char*)outv + (size_t)rowBase * 256 + byteoff) = v;
      }
    }
  }
}

// ---------------- launch ----------------

extern "C" void kernel_launch(void* const* d_in, const int* in_sizes, int n_in,
                              void* d_out, int out_size, void* d_ws, size_t ws_size,
                              hipStream_t stream) {
  const float* x = (const float*)d_in[0];
  const int* ei = (const int*)d_in[1];
  const float* w1[3] = {(const float*)d_in[2], (const float*)d_in[6], (const float*)d_in[10]};
  const float* b1[3] = {(const float*)d_in[3], (const float*)d_in[7], (const float*)d_in[11]};
  const float* w2[3] = {(const float*)d_in[4], (const float*)d_in[8], (const float*)d_in[12]};
  const float* b2[3] = {(const float*)d_in[5], (const float*)d_in[9], (const float*)d_in[13]};
  const float* wout = (const float*)d_in[14];
  const float* bout = (const float*)d_in[15];
  float* out = (float*)d_out;

  char* ws = (char*)d_ws;
  size_t off = 0;
  f16* B0  = (f16*)(ws + off); off += (size_t)N_NODES * 128 * 2;
  f16* B1  = (f16*)(ws + off); off += (size_t)N_NODES * 128 * 2;
  f16* x16 = (f16*)(ws + off); off += (size_t)N_NODES * 128 * 2;
  f16* Wt[6];
  for (int i = 0; i < 6; ++i) { Wt[i] = (f16*)(ws + off); off += 128 * 128 * 2; }
  int* offs   = (int*)(ws + off); off += (size_t)N_NODES * 4;
  int* counts = (int*)(ws + off); off += (size_t)N_NODES * 4;
  int* scur   = (int*)(ws + off); off += 1024;
  int* srcs   = (int*)(ws + off); off += (size_t)N_EDGES * 4;
  int2* bpair = (int2*)(ws + off); off += (size_t)NSLICE * CAP * 8;

  // ---- CSR build: bucket(+wprep+cvt) -> per-slice LDS CSR ----
  hipMemsetAsync(scur, 0, 1024, stream);
  WPack wp;
  const float* wsrc[6] = {w1[0], w2[0], w1[1], w2[1], w1[2], w2[2]};
  for (int i = 0; i < 6; ++i) { wp.w[i] = wsrc[i]; wp.o[i] = Wt[i]; }
  bucket_cvt_kernel<<<NACH + NWPREP + NCVT, 256, 0, stream>>>(ei, bpair, scur, wp, x, x16);
  csr_slice_kernel<<<NSLICE, 1024, 0, stream>>>(bpair, scur, offs, counts, srcs);

  int aggGrid = (N_NODES * 16) / 256;    // 6250 (16-lane group per node)
  int lyrGrid = (N_NODES + 127) / 128;   // 782

  // layer 1
  aggregate_kernel<<<aggGrid, 256, 0, stream>>>(x16, offs, counts, srcs, B0, N_NODES);
  layer_kernel<0><<<lyrGrid, 512, 0, stream>>>(B0, Wt[0], Wt[1], b1[0], b2[0], B1, nullptr, nullptr, N_NODES);
  // layer 2
  aggregate_kernel<<<aggGrid, 256, 0, stream>>>(B1, offs, counts, srcs, B0, N_NODES);
  layer_kernel<0><<<lyrGrid, 512, 0, stream>>>(B0, Wt[2], Wt[3], b1[1], b2[1], B1, nullptr, nullptr, N_NODES);
  // layer 3 (+ fused w_out projection)
  aggregate_kernel<<<aggGrid, 256, 0, stream>>>(B1, offs, counts, srcs, B0, N_NODES);
  layer_kernel<1><<<lyrGrid, 512, 0, stream>>>(B0, Wt[4], Wt[5], b1[2], b2[2], out, wout, bout, N_NODES);
}